// Round 1
// baseline (46.504 us; speedup 1.0000x reference)
//
#include <hip/hip_runtime.h>
#include <hip/hip_bf16.h>

// VDPReLU:
//   mu_out   = relu(mu_in)                         (32,64,128) f32
//   Sigma_out = Sigma_in * mask_i * mask_j          (32,64,128,128) f32
// where mask = (mu_in > 0). Purely memory-bound: ~270 MB HBM traffic.
//
// One block per (b,c) slice: 2048 blocks x 256 threads.
// - threads 0..127 load the mu row, write mu_out, stash 0/1 mask in LDS.
// - all 256 threads stream the 16384-float Sigma slice as 4096 float4's
//   (16 iterations). Column mask (4 values) is per-thread constant ->
//   registers; row mask is an LDS broadcast (conflict-free).

__global__ __launch_bounds__(256) void vdp_relu_kernel(
    const float* __restrict__ mu_in,
    const float* __restrict__ sigma_in,
    float* __restrict__ mu_out,
    float* __restrict__ sigma_out)
{
    const int bc  = blockIdx.x;   // 0..2047  (b*64 + c)
    const int tid = threadIdx.x;  // 0..255

    __shared__ float s_mask[128];

    // Load mu row, emit relu, build 0/1 mask.
    if (tid < 128) {
        float m = mu_in[bc * 128 + tid];
        mu_out[bc * 128 + tid] = (m > 0.0f) ? m : 0.0f;
        s_mask[tid] = (m > 0.0f) ? 1.0f : 0.0f;
    }
    __syncthreads();

    // Per-thread column mask (j-group fixed: j4 = tid & 31).
    const int j4 = (tid & 31) * 4;
    const float mj0 = s_mask[j4 + 0];
    const float mj1 = s_mask[j4 + 1];
    const float mj2 = s_mask[j4 + 2];
    const float mj3 = s_mask[j4 + 3];

    const float4* __restrict__ src =
        reinterpret_cast<const float4*>(sigma_in) + (size_t)bc * 4096;
    float4* __restrict__ dst =
        reinterpret_cast<float4*>(sigma_out) + (size_t)bc * 4096;

    const int row_base = tid >> 5;  // 0..7

#pragma unroll
    for (int it = 0; it < 16; ++it) {
        const int v = it * 256 + tid;          // float4 index 0..4095
        const float mi = s_mask[it * 8 + row_base];  // broadcast read
        float4 s = src[v];
        s.x *= mi * mj0;
        s.y *= mi * mj1;
        s.z *= mi * mj2;
        s.w *= mi * mj3;
        dst[v] = s;
    }
}

extern "C" void kernel_launch(void* const* d_in, const int* in_sizes, int n_in,
                              void* d_out, int out_size, void* d_ws, size_t ws_size,
                              hipStream_t stream)
{
    const float* mu_in    = (const float*)d_in[0];   // 32*64*128
    const float* sigma_in = (const float*)d_in[1];   // 32*64*128*128

    float* mu_out    = (float*)d_out;                 // first 262144 floats
    float* sigma_out = (float*)d_out + 32 * 64 * 128; // remaining 33554432

    dim3 grid(32 * 64);  // one block per (b,c)
    dim3 block(256);
    vdp_relu_kernel<<<grid, block, 0, stream>>>(mu_in, sigma_in, mu_out, sigma_out);
}

// Round 3
// 44.503 us; speedup vs baseline: 1.0450x; 1.0450x over previous
//
#include <hip/hip_runtime.h>
#include <hip/hip_bf16.h>

// VDPReLU:
//   mu_out    = relu(mu_in)                        (32,64,128) f32
//   Sigma_out = Sigma_in * mask_i * mask_j         (32,64,128,128) f32
// where mask = (mu_in > 0). Purely memory-bound: ~135 MB read + ~135 MB write.
//
// Cache insight (round 1 counters): Sigma_in (134 MB) fits in the 256 MB
// Infinity Cache, but regular stores of Sigma_out (134 MB) evict it
// (FETCH_SIZE showed 66 MB of HBM re-reads). Non-temporal stores keep
// Sigma_out out of L3 so Sigma_in stays resident -> reads become L3 hits,
// kernel is write-bound only (~135 MB @ HBM).
//
// Note: __builtin_nontemporal_store needs a native vector type, not HIP's
// float4 class -> use ext_vector_type(4).

typedef float f32x4 __attribute__((ext_vector_type(4)));

__global__ __launch_bounds__(256) void vdp_relu_kernel(
    const float* __restrict__ mu_in,
    const float* __restrict__ sigma_in,
    float* __restrict__ mu_out,
    float* __restrict__ sigma_out)
{
    const int bc  = blockIdx.x;   // 0..2047  (b*64 + c)
    const int tid = threadIdx.x;  // 0..255

    __shared__ float s_mask[128];

    // Load mu row, emit relu, build 0/1 mask.
    if (tid < 128) {
        float m = mu_in[bc * 128 + tid];
        mu_out[bc * 128 + tid] = (m > 0.0f) ? m : 0.0f;
        s_mask[tid] = (m > 0.0f) ? 1.0f : 0.0f;
    }
    __syncthreads();

    // Per-thread column mask (j-group fixed: j4 = tid & 31).
    const int j4 = (tid & 31) * 4;
    const float mj0 = s_mask[j4 + 0];
    const float mj1 = s_mask[j4 + 1];
    const float mj2 = s_mask[j4 + 2];
    const float mj3 = s_mask[j4 + 3];

    const f32x4* __restrict__ src =
        reinterpret_cast<const f32x4*>(sigma_in) + (size_t)bc * 4096;
    f32x4* __restrict__ dst =
        reinterpret_cast<f32x4*>(sigma_out) + (size_t)bc * 4096;

    const int row_base = tid >> 5;  // 0..7

#pragma unroll
    for (int it = 0; it < 16; ++it) {
        const int v = it * 256 + tid;               // float4 index 0..4095
        const float mi = s_mask[it * 8 + row_base]; // broadcast read
        f32x4 s = src[v];
        s.x *= mi * mj0;
        s.y *= mi * mj1;
        s.z *= mi * mj2;
        s.w *= mi * mj3;
        // Non-temporal: don't allocate Sigma_out in L2/L3 so Sigma_in
        // stays Infinity-Cache-resident across replays.
        __builtin_nontemporal_store(s, &dst[v]);
    }
}

extern "C" void kernel_launch(void* const* d_in, const int* in_sizes, int n_in,
                              void* d_out, int out_size, void* d_ws, size_t ws_size,
                              hipStream_t stream)
{
    const float* mu_in    = (const float*)d_in[0];   // 32*64*128
    const float* sigma_in = (const float*)d_in[1];   // 32*64*128*128

    float* mu_out    = (float*)d_out;                 // first 262144 floats
    float* sigma_out = (float*)d_out + 32 * 64 * 128; // remaining 33554432

    dim3 grid(32 * 64);  // one block per (b,c)
    dim3 block(256);
    vdp_relu_kernel<<<grid, block, 0, stream>>>(mu_in, sigma_in, mu_out, sigma_out);
}